// Round 7
// baseline (315.235 us; speedup 1.0000x reference)
//
#include <hip/hip_runtime.h>
#include <hip/hip_bf16.h>
#include <stdint.h>

#define BB 1024
#define NN 8192
#define KK 4096

typedef float vf4 __attribute__((ext_vector_type(4)));
typedef int   vi4 __attribute__((ext_vector_type(4)));
typedef int   vi2 __attribute__((ext_vector_type(2)));

// ---- workspace layout ----
// [0,32KB)              pos[N] int
// [32KB,33KB)           frozen[256] u32   (bit e of word e>>5: pos[e]>=0)
// [64KB, 64KB+1MB)      wsu: packed substituted u bits, 256 u32/row
// [64KB+1MB, 64KB+2MB)  wsr: packed raw u_random bits
// [64KB+2MB, 64KB+3MB)  wsy: packed butterfly output y
#define POS_OFF    0
#define FROZEN_OFF (32*1024)
#define U_OFF      (64*1024)
#define R_OFF      (64*1024 + 1024*1024)
#define Y_OFF      (64*1024 + 2*1024*1024)
#define WS_NEED    (64*1024 + 3*1024*1024)

__global__ void init_pos_kernel(int* __restrict__ pos) {
    int i = blockIdx.x * blockDim.x + threadIdx.x;
    if (i < NN) pos[i] = -1;
}
__global__ void scatter_pos_kernel(const int* __restrict__ info_set, int* __restrict__ pos) {
    int k = blockIdx.x * blockDim.x + threadIdx.x;
    if (k < KK) pos[info_set[k]] = k;
}
__global__ void frozen_kernel(const int* __restrict__ pos, uint32_t* __restrict__ frozen) {
    const int gi   = blockIdx.x * blockDim.x + threadIdx.x;   // 8192 threads
    const int lane = threadIdx.x & 63;
    unsigned long long m = __ballot(pos[gi] >= 0);
    if (lane == 0) {
        const int w = gi >> 5;                 // even
        frozen[w]     = (uint32_t)m;
        frozen[w + 1] = (uint32_t)(m >> 32);
    }
}

__device__ __forceinline__ vf4 mk4(float a, float b, float c, float d) {
    vf4 v; v.x = a; v.y = b; v.z = c; v.w = d; return v;
}
__device__ __forceinline__ uint32_t merge8(uint32_t x) {
    // 4-bit nibble per lane -> 32-bit word, valid in lanes with (lane&7)==0.
    x |= ((uint32_t)__shfl_xor((int)x, 1)) << 4;
    x |= ((uint32_t)__shfl_xor((int)x, 2)) << 8;
    x |= ((uint32_t)__shfl_xor((int)x, 4)) << 16;
    return x;
}

// ---- Kernel A: one wave per row. Pack bits, butterfly, emit packed words. ----
__global__ __launch_bounds__(64) void pack_butterfly_kernel(
    const float* __restrict__ info_bits,
    const int*   __restrict__ u_random,
    const int*   __restrict__ pos,
    uint32_t*    __restrict__ wsu,
    uint32_t*    __restrict__ wsr,
    uint32_t*    __restrict__ wsy)
{
    __shared__ uint32_t ywu[256];
    __shared__ uint32_t ywr[256];

    const int b    = blockIdx.x;
    const int lane = threadIdx.x;

    const vi4*   ur4p  = (const vi4*)(u_random + (size_t)b * NN);
    const vi4*   pos4p = (const vi4*)pos;
    const float* ibrow = info_bits + (size_t)b * KK;

    #pragma unroll 8
    for (int it = 0; it < 32; ++it) {
        const int idx4 = it * 64 + lane;
        const vi4 ur = ur4p[idx4];
        const vi4 kk = pos4p[idx4];

        int u0 = ur.x, u1 = ur.y, u2 = ur.z, u3 = ur.w;
        if (kk.x >= 0) u0 = ibrow[kk.x] > 0.5f;
        if (kk.y >= 0) u1 = ibrow[kk.y] > 0.5f;
        if (kk.z >= 0) u2 = ibrow[kk.z] > 0.5f;
        if (kk.w >= 0) u3 = ibrow[kk.w] > 0.5f;

        uint32_t xu = merge8((uint32_t)(u0 | (u1 << 1) | (u2 << 2) | (u3 << 3)));
        uint32_t xr = merge8((uint32_t)(ur.x | (ur.y << 1) | (ur.z << 2) | (ur.w << 3)));
        if ((lane & 7) == 0) {
            ywu[it * 8 + (lane >> 3)] = xu;   // word = idx4>>3; elem 32w+c <-> bit c
            ywr[it * 8 + (lane >> 3)] = xr;
        }
    }
    __syncthreads();   // single wave: just drains LDS counters

    uint32_t W0 = ywu[lane];
    uint32_t W1 = ywu[lane + 64];
    uint32_t W2 = ywu[lane + 128];
    uint32_t W3 = ywu[lane + 192];

    // pre-butterfly packed outputs
    uint32_t* su = wsu + (size_t)b * 256;
    uint32_t* sr = wsr + (size_t)b * 256;
    su[lane] = W0; su[lane + 64] = W1; su[lane + 128] = W2; su[lane + 192] = W3;
    sr[lane]       = ywr[lane];
    sr[lane + 64]  = ywr[lane + 64];
    sr[lane + 128] = ywr[lane + 128];
    sr[lane + 192] = ywr[lane + 192];

    // ---- verified superset-XOR butterfly ----
    #define INWORD(W) \
        W ^= (W >> 1)  & 0x55555555u; \
        W ^= (W >> 2)  & 0x33333333u; \
        W ^= (W >> 4)  & 0x0F0F0F0Fu; \
        W ^= (W >> 8)  & 0x00FF00FFu; \
        W ^= (W >> 16) & 0x0000FFFFu;
    INWORD(W0) INWORD(W1) INWORD(W2) INWORD(W3)
    #undef INWORD

    #pragma unroll
    for (int wb = 0; wb < 6; ++wb) {
        const bool keep = ((lane >> wb) & 1);
        uint32_t p0 = (uint32_t)__shfl_xor((int)W0, 1 << wb);
        uint32_t p1 = (uint32_t)__shfl_xor((int)W1, 1 << wb);
        uint32_t p2 = (uint32_t)__shfl_xor((int)W2, 1 << wb);
        uint32_t p3 = (uint32_t)__shfl_xor((int)W3, 1 << wb);
        if (!keep) { W0 ^= p0; W1 ^= p1; W2 ^= p2; W3 ^= p3; }
    }
    W0 ^= W1; W2 ^= W3;   // word-index bit 6
    W0 ^= W2; W1 ^= W3;   // word-index bit 7

    uint32_t* sy = wsy + (size_t)b * 256;
    sy[lane] = W0; sy[lane + 64] = W1; sy[lane + 128] = W2; sy[lane + 192] = W3;
}

// ---- Kernel B: pure streaming expansion. No barriers, no LDS, no gathers. ----
__global__ __launch_bounds__(512) void expand_kernel(
    const uint32_t* __restrict__ wsu,
    const uint32_t* __restrict__ wsr,
    const uint32_t* __restrict__ wsy,
    const uint32_t* __restrict__ frozen,
    float*          __restrict__ out)
{
    const int b = blockIdx.x;
    const int t = threadIdx.x;

    vf4* x4 = (vf4*)(out)                 + (size_t)b * (NN / 4);
    vf4* f4 = (vf4*)(out + (size_t)BB*NN) + (size_t)b * (NN / 4);
    vf4* u4 = (vf4*)(out + 2ull*BB*NN)    + (size_t)b * (NN / 4);
    vf4* p4 = (vf4*)(out + 3ull*BB*NN)    + (size_t)b * (NN / 2);
    vf4* r4 = (vf4*)(out + 5ull*BB*NN)    + (size_t)b * (NN / 2);

    const uint32_t* yu = wsu + (size_t)b * 256;
    const uint32_t* yr = wsr + (size_t)b * 256;
    const uint32_t* yy = wsy + (size_t)b * 256;

    // u, f  (element 4*idx4+j = bit (idx4&7)*4+j of word idx4>>3)
    #pragma unroll
    for (int it = 0; it < 4; ++it) {
        const int idx4 = it * 512 + t;
        const int w  = idx4 >> 3;
        const int sh = (idx4 & 7) * 4;
        const uint32_t wu = yu[w] >> sh;
        const uint32_t wf = frozen[w] >> sh;
        const float u0 = (float)(wu & 1u),        u1 = (float)((wu >> 1) & 1u);
        const float u2 = (float)((wu >> 2) & 1u), u3 = (float)((wu >> 3) & 1u);
        u4[idx4] = mk4(u0, u1, u2, u3);
        f4[idx4] = mk4((wf & 1u)        ? 2.0f : u0,
                       ((wf >> 1) & 1u) ? 2.0f : u1,
                       ((wf >> 2) & 1u) ? 2.0f : u2,
                       ((wf >> 3) & 1u) ? 2.0f : u3);
    }

    // x[i] = y[rev13(i)]  (verified Stage C, global y instead of LDS)
    #pragma unroll
    for (int it = 0; it < 4; ++it) {
        const int s = it * 512 + t;
        const uint32_t q = __builtin_bitreverse32((uint32_t)s) >> 21;  // rev11(s)
        const int w   = (int)(q >> 5);
        const int bsh = (int)(q & 31u);
        const float x0 = (float)((yy[w]       >> bsh) & 1u);
        const float x1 = (float)((yy[w + 128] >> bsh) & 1u);
        const float x2 = (float)((yy[w + 64]  >> bsh) & 1u);
        const float x3 = (float)((yy[w + 192] >> bsh) & 1u);
        x4[s] = mk4(x0, x1, x2, x3);
    }

    // r  (elements 2j,2j+1 = bits (j&15)*2, +1 of word j>>4)
    #pragma unroll
    for (int c = 0; c < 8; ++c) {
        const int j = c * 512 + t;
        const uint32_t wr = yr[j >> 4] >> ((j & 15) * 2);
        const float b0 = (float)(wr & 1u), b1 = (float)((wr >> 1) & 1u);
        r4[j] = mk4(1.0f - b0, b0, 1.0f - b1, b1);
    }

    // p = 0.5
    const vf4 half = mk4(0.5f, 0.5f, 0.5f, 0.5f);
    #pragma unroll
    for (int c = 0; c < 8; ++c)
        p4[c * 512 + t] = half;
}

// ---- Fallback: R6 monolithic kernel (used only if ws_size < WS_NEED) ----
__global__ __launch_bounds__(512) void polar_main_kernel(
    const float* __restrict__ info_bits,
    const int*   __restrict__ u_random,
    const int*   __restrict__ pos,
    float*       __restrict__ out)
{
    __shared__ uint32_t yw[256];
    const int b = blockIdx.x, t = threadIdx.x;
    const int lane = t & 63, ww = t >> 6;

    vf4* x4 = (vf4*)(out)                 + (size_t)b * (NN / 4);
    vf4* f4 = (vf4*)(out + (size_t)BB*NN) + (size_t)b * (NN / 4);
    vf4* u4 = (vf4*)(out + 2ull*BB*NN)    + (size_t)b * (NN / 4);
    vf4* p4 = (vf4*)(out + 3ull*BB*NN)    + (size_t)b * (NN / 2);
    vf4* r4 = (vf4*)(out + 5ull*BB*NN)    + (size_t)b * (NN / 2);

    const vi4* ur4p = (const vi4*)(u_random + (size_t)b * NN);
    const vi2* ur2p = (const vi2*)(u_random + (size_t)b * NN);
    const vi4* pos4p = (const vi4*)pos;
    const float* ibrow = info_bits + (size_t)b * KK;

    #pragma unroll
    for (int it = 0; it < 4; ++it) {
        const int idx4 = it * 512 + t;
        const vi4 ur = ur4p[idx4];
        const vi4 kk = pos4p[idx4];
        int u0 = ur.x, u1 = ur.y, u2 = ur.z, u3 = ur.w;
        int f0 = u0, f1 = u1, f2 = u2, f3 = u3;
        if (kk.x >= 0) { u0 = ibrow[kk.x] > 0.5f; f0 = 2; }
        if (kk.y >= 0) { u1 = ibrow[kk.y] > 0.5f; f1 = 2; }
        if (kk.z >= 0) { u2 = ibrow[kk.z] > 0.5f; f2 = 2; }
        if (kk.w >= 0) { u3 = ibrow[kk.w] > 0.5f; f3 = 2; }
        u4[idx4] = mk4((float)u0, (float)u1, (float)u2, (float)u3);
        f4[idx4] = mk4((float)f0, (float)f1, (float)f2, (float)f3);
        uint32_t x = merge8((uint32_t)(u0 | (u1 << 1) | (u2 << 2) | (u3 << 3)));
        if ((lane & 7) == 0) yw[it * 64 + ww * 8 + (lane >> 3)] = x;
    }
    __syncthreads();
    if (ww == 0) {
        uint32_t W0 = yw[lane], W1 = yw[lane + 64], W2 = yw[lane + 128], W3 = yw[lane + 192];
        #define INWORD(W) \
            W ^= (W >> 1)  & 0x55555555u; \
            W ^= (W >> 2)  & 0x33333333u; \
            W ^= (W >> 4)  & 0x0F0F0F0Fu; \
            W ^= (W >> 8)  & 0x00FF00FFu; \
            W ^= (W >> 16) & 0x0000FFFFu;
        INWORD(W0) INWORD(W1) INWORD(W2) INWORD(W3)
        #undef INWORD
        #pragma unroll
        for (int wb = 0; wb < 6; ++wb) {
            const bool keep = ((lane >> wb) & 1);
            uint32_t p0 = (uint32_t)__shfl_xor((int)W0, 1 << wb);
            uint32_t p1 = (uint32_t)__shfl_xor((int)W1, 1 << wb);
            uint32_t p2 = (uint32_t)__shfl_xor((int)W2, 1 << wb);
            uint32_t p3 = (uint32_t)__shfl_xor((int)W3, 1 << wb);
            if (!keep) { W0 ^= p0; W1 ^= p1; W2 ^= p2; W3 ^= p3; }
        }
        W0 ^= W1; W2 ^= W3; W0 ^= W2; W1 ^= W3;
        yw[lane] = W0; yw[lane + 64] = W1; yw[lane + 128] = W2; yw[lane + 192] = W3;
    }
    __syncthreads();
    #pragma unroll
    for (int it = 0; it < 4; ++it) {
        const int s = it * 512 + t;
        const uint32_t q = __builtin_bitreverse32((uint32_t)s) >> 21;
        const int w = (int)(q >> 5), bsh = (int)(q & 31u);
        x4[s] = mk4((float)((yw[w] >> bsh) & 1u), (float)((yw[w + 128] >> bsh) & 1u),
                    (float)((yw[w + 64] >> bsh) & 1u), (float)((yw[w + 192] >> bsh) & 1u));
    }
    #pragma unroll
    for (int c = 0; c < 8; ++c) {
        const int j = c * 512 + t;
        const vi2 ur = ur2p[j];
        r4[j] = mk4((float)(1 - ur.x), (float)ur.x, (float)(1 - ur.y), (float)ur.y);
    }
    const vf4 half = mk4(0.5f, 0.5f, 0.5f, 0.5f);
    #pragma unroll
    for (int c = 0; c < 8; ++c)
        p4[c * 512 + t] = half;
}

extern "C" void kernel_launch(void* const* d_in, const int* in_sizes, int n_in,
                              void* d_out, int out_size, void* d_ws, size_t ws_size,
                              hipStream_t stream) {
    const float* info_bits = (const float*)d_in[0];
    const int*   u_random  = (const int*)  d_in[1];
    const int*   info_set  = (const int*)  d_in[2];
    float*       out       = (float*)d_out;

    int*      pos    = (int*)((char*)d_ws + POS_OFF);
    uint32_t* frozen = (uint32_t*)((char*)d_ws + FROZEN_OFF);
    uint32_t* wsu    = (uint32_t*)((char*)d_ws + U_OFF);
    uint32_t* wsr    = (uint32_t*)((char*)d_ws + R_OFF);
    uint32_t* wsy    = (uint32_t*)((char*)d_ws + Y_OFF);

    init_pos_kernel<<<NN / 256, 256, 0, stream>>>(pos);
    scatter_pos_kernel<<<KK / 256, 256, 0, stream>>>(info_set, pos);

    if (ws_size >= (size_t)WS_NEED) {
        frozen_kernel<<<NN / 256, 256, 0, stream>>>(pos, frozen);
        pack_butterfly_kernel<<<BB, 64, 0, stream>>>(info_bits, u_random, pos, wsu, wsr, wsy);
        expand_kernel<<<BB, 512, 0, stream>>>(wsu, wsr, wsy, frozen, out);
    } else {
        polar_main_kernel<<<BB, 512, 0, stream>>>(info_bits, u_random, pos, out);
    }
}

// Round 8
// 276.341 us; speedup vs baseline: 1.1407x; 1.1407x over previous
//
#include <hip/hip_runtime.h>
#include <hip/hip_bf16.h>
#include <stdint.h>

#define BB 1024
#define NN 8192
#define KK 4096

typedef float vf4 __attribute__((ext_vector_type(4)));
typedef int   vi4 __attribute__((ext_vector_type(4)));

// pos[n] = k if n == info_set[k] else -1  (info_set sorted, unique)
__global__ void init_pos_kernel(int* __restrict__ pos) {
    int i = blockIdx.x * blockDim.x + threadIdx.x;
    if (i < NN) pos[i] = -1;
}
__global__ void scatter_pos_kernel(const int* __restrict__ info_set, int* __restrict__ pos) {
    int k = blockIdx.x * blockDim.x + threadIdx.x;
    if (k < KK) pos[info_set[k]] = k;
}

__device__ __forceinline__ vf4 mk4(float a, float b, float c, float d) {
    vf4 v; v.x = a; v.y = b; v.z = c; v.w = d; return v;
}
__device__ __forceinline__ uint32_t merge8(uint32_t x) {
    // 4-bit nibble per lane -> 32-bit word, valid in lanes with (lane&7)==0.
    x |= ((uint32_t)__shfl_xor((int)x, 1)) << 4;
    x |= ((uint32_t)__shfl_xor((int)x, 2)) << 8;
    x |= ((uint32_t)__shfl_xor((int)x, 4)) << 16;
    return x;
}

// One block per row, 512 threads = 8 waves, ONE barrier.
// Pre-barrier:  load u_random+pos (vi4), gather info_bits; store u,f (vf4,
//               lane-contiguous); pack substituted bits -> ywu[256] and raw
//               bits -> ywr[256] via nibble+shfl merge.
// Post-barrier: EVERY wave redundantly butterflies the 256 packed words
//               (4 ds_read/lane + ~60 VALU + shfl stages); Stage C needs LDS
//               word rev6(lane) = per-thread constant -> 4 __shfl total;
//               r expanded from ywr; p constant. No second barrier.
__global__ __launch_bounds__(512) void polar_main_kernel(
    const float* __restrict__ info_bits,   // (B,K) 0.0/1.0
    const int*   __restrict__ u_random,    // (B,N) 0/1
    const int*   __restrict__ pos,         // (N,)
    float*       __restrict__ out)
{
    __shared__ uint32_t ywu[256];
    __shared__ uint32_t ywr[256];

    const int b    = blockIdx.x;
    const int t    = threadIdx.x;
    const int lane = t & 63;
    const int ww   = t >> 6;

    vf4* x4 = (vf4*)(out)                 + (size_t)b * (NN / 4);
    vf4* f4 = (vf4*)(out + (size_t)BB*NN) + (size_t)b * (NN / 4);
    vf4* u4 = (vf4*)(out + 2ull*BB*NN)    + (size_t)b * (NN / 4);
    vf4* p4 = (vf4*)(out + 3ull*BB*NN)    + (size_t)b * (NN / 2);
    vf4* r4 = (vf4*)(out + 5ull*BB*NN)    + (size_t)b * (NN / 2);

    const vi4*   ur4p  = (const vi4*)(u_random + (size_t)b * NN);
    const vi4*   pos4p = (const vi4*)pos;
    const float* ibrow = info_bits + (size_t)b * KK;

    // ---- Stage A: u, f, bit-pack (substituted + raw) ----
    #pragma unroll
    for (int it = 0; it < 4; ++it) {
        const int idx4 = it * 512 + t;           // coalesced across lanes
        const vi4 ur = ur4p[idx4];
        const vi4 kk = pos4p[idx4];

        int u0 = ur.x, u1 = ur.y, u2 = ur.z, u3 = ur.w;
        int f0 = u0,   f1 = u1,   f2 = u2,   f3 = u3;
        if (kk.x >= 0) { u0 = ibrow[kk.x] > 0.5f; f0 = 2; }
        if (kk.y >= 0) { u1 = ibrow[kk.y] > 0.5f; f1 = 2; }
        if (kk.z >= 0) { u2 = ibrow[kk.z] > 0.5f; f2 = 2; }
        if (kk.w >= 0) { u3 = ibrow[kk.w] > 0.5f; f3 = 2; }

        u4[idx4] = mk4((float)u0, (float)u1, (float)u2, (float)u3);
        f4[idx4] = mk4((float)f0, (float)f1, (float)f2, (float)f3);

        uint32_t xu = merge8((uint32_t)(u0 | (u1 << 1) | (u2 << 2) | (u3 << 3)));
        uint32_t xr = merge8((uint32_t)(ur.x | (ur.y << 1) | (ur.z << 2) | (ur.w << 3)));
        if ((lane & 7) == 0) {
            ywu[it * 64 + ww * 8 + (lane >> 3)] = xu;   // word = idx4>>3
            ywr[it * 64 + ww * 8 + (lane >> 3)] = xr;
        }
    }
    __syncthreads();

    // ---- Stage B: superset-XOR butterfly, redundantly in every wave ----
    uint32_t W0 = ywu[lane];
    uint32_t W1 = ywu[lane + 64];
    uint32_t W2 = ywu[lane + 128];
    uint32_t W3 = ywu[lane + 192];

    #define INWORD(W) \
        W ^= (W >> 1)  & 0x55555555u; \
        W ^= (W >> 2)  & 0x33333333u; \
        W ^= (W >> 4)  & 0x0F0F0F0Fu; \
        W ^= (W >> 8)  & 0x00FF00FFu; \
        W ^= (W >> 16) & 0x0000FFFFu;
    INWORD(W0) INWORD(W1) INWORD(W2) INWORD(W3)
    #undef INWORD

    #pragma unroll
    for (int wb = 0; wb < 6; ++wb) {
        const bool keep = ((lane >> wb) & 1);
        uint32_t q0 = (uint32_t)__shfl_xor((int)W0, 1 << wb);
        uint32_t q1 = (uint32_t)__shfl_xor((int)W1, 1 << wb);
        uint32_t q2 = (uint32_t)__shfl_xor((int)W2, 1 << wb);
        uint32_t q3 = (uint32_t)__shfl_xor((int)W3, 1 << wb);
        if (!keep) { W0 ^= q0; W1 ^= q1; W2 ^= q2; W3 ^= q3; }
    }
    W0 ^= W1; W2 ^= W3;   // word-index bit 6
    W0 ^= W2; W1 ^= W3;   // word-index bit 7
    // Now lane L holds y-words {L, L+64, L+128, L+192} in W0..W3.

    // ---- Stage C: x[i] = y[rev13(i)] ----
    // w = rev6(lane) is per-thread constant: fetch the 4 needed words once.
    const int w = (int)(__builtin_bitreverse32((uint32_t)lane) >> 26);  // rev6(lane)
    const uint32_t V0 = (uint32_t)__shfl((int)W0, w);   // yw[w]
    const uint32_t V1 = (uint32_t)__shfl((int)W1, w);   // yw[w+64]
    const uint32_t V2 = (uint32_t)__shfl((int)W2, w);   // yw[w+128]
    const uint32_t V3 = (uint32_t)__shfl((int)W3, w);   // yw[w+192]

    #pragma unroll
    for (int it = 0; it < 4; ++it) {
        const int s = it * 512 + t;
        // bsh = rev5(it*8+ww), wave-uniform; keep exact R6 arithmetic:
        const uint32_t q = __builtin_bitreverse32((uint32_t)s) >> 21;  // rev11(s)
        const int bsh = (int)(q & 31u);
        const float x0 = (float)((V0 >> bsh) & 1u);
        const float x1 = (float)((V2 >> bsh) & 1u);
        const float x2 = (float)((V1 >> bsh) & 1u);
        const float x3 = (float)((V3 >> bsh) & 1u);
        x4[s] = mk4(x0, x1, x2, x3);
    }

    // ---- Stage R: r from packed raw bits (elements 2j,2j+1 = bits (j&15)*2,+1
    //               of ywr[j>>4]; 16 consecutive lanes share a word) ----
    #pragma unroll
    for (int c = 0; c < 8; ++c) {
        const int j = c * 512 + t;               // vf4 index, 4096 total
        const uint32_t wr = ywr[j >> 4] >> ((j & 15) * 2);
        const float b0 = (float)(wr & 1u), b1 = (float)((wr >> 1) & 1u);
        r4[j] = mk4(1.0f - b0, b0, 1.0f - b1, b1);
    }

    // ---- Stage P: constant 0.5 (4096 vf4 per row) ----
    const vf4 half = mk4(0.5f, 0.5f, 0.5f, 0.5f);
    #pragma unroll
    for (int c = 0; c < 8; ++c)
        p4[c * 512 + t] = half;
}

extern "C" void kernel_launch(void* const* d_in, const int* in_sizes, int n_in,
                              void* d_out, int out_size, void* d_ws, size_t ws_size,
                              hipStream_t stream) {
    const float* info_bits = (const float*)d_in[0];   // (B,K) float32
    const int*   u_random  = (const int*)  d_in[1];   // (B,N) int32
    const int*   info_set  = (const int*)  d_in[2];   // (K,)  int32
    float*       out       = (float*)d_out;
    int*         pos       = (int*)d_ws;              // N ints = 32 KB

    init_pos_kernel<<<NN / 256, 256, 0, stream>>>(pos);
    scatter_pos_kernel<<<KK / 256, 256, 0, stream>>>(info_set, pos);
    polar_main_kernel<<<BB, 512, 0, stream>>>(info_bits, u_random, pos, out);
}